// Round 19
// baseline (920.577 us; speedup 1.0000x reference)
//
#include <hip/hip_runtime.h>
#include <math.h>

#define NATOM 16384
#define NEDGE 262144
#define HID 128
#define NG 50
#define NI 6

typedef _Float16 h8_t __attribute__((ext_vector_type(8)));
typedef _Float16 h4_t __attribute__((ext_vector_type(4)));
typedef float    f4_t __attribute__((ext_vector_type(4)));

__device__ __forceinline__ float ssp_f(float v) {
    float e = __expf(-fabsf(v));
    return fmaxf(v, 0.0f) + __logf(1.0f + e) - 0.69314718055994531f;
}

// ---------------- counting sort by dst ----------------
__global__ void fill0(float* __restrict__ p, int n4) {
    int i = blockIdx.x * 256 + threadIdx.x;
    if (i < n4) ((float4*)p)[i] = make_float4(0.f, 0.f, 0.f, 0.f);
}

__global__ void hist_k(const int* __restrict__ ei, int* __restrict__ cnt) {
    int e = blockIdx.x * 256 + threadIdx.x;
    if (e < NEDGE) atomicAdd(&cnt[ei[NEDGE + e]], 1);
}

__global__ void scan_k(const int* __restrict__ cnt, int* __restrict__ offs) {
    __shared__ int part[256];
    int t = threadIdx.x;
    int base = t * 64;
    int s = 0;
    for (int i = 0; i < 64; ++i) s += cnt[base + i];
    part[t] = s;
    __syncthreads();
    for (int off = 1; off < 256; off <<= 1) {
        int v = (t >= off) ? part[t - off] : 0;
        __syncthreads();
        part[t] += v;
        __syncthreads();
    }
    int r = part[t] - s;
    for (int i = 0; i < 64; ++i) { offs[base + i] = r; r += cnt[base + i]; }
    if (t == 255) offs[NATOM] = r;
}

__global__ void scatter_k(const int* __restrict__ ei, const int* __restrict__ offs,
                          int* __restrict__ cnt, int* __restrict__ sSrc, int* __restrict__ sDst) {
    int e = blockIdx.x * 256 + threadIdx.x;
    if (e >= NEDGE) return;
    int d = ei[NEDGE + e];
    int r = atomicAdd(&cnt[d], 1);
    int j = offs[d] + r;
    sSrc[j] = ei[e];
    sDst[j] = d;
}

// ---------------- edge precompute: gaussians fp16 edge-major [e][64] ----------------
__global__ void edge_pre(const float* __restrict__ pos,
                         const int* __restrict__ sSrc, const int* __restrict__ sDst,
                         _Float16* __restrict__ ea, float* __restrict__ Cb) {
    int j = blockIdx.x * 256 + threadIdx.x;
    if (j >= NEDGE) return;
    int s = sSrc[j], dd = sDst[j];
    float dx = pos[3*s]   - pos[3*dd];
    float dy = pos[3*s+1] - pos[3*dd+1];
    float dz = pos[3*s+2] - pos[3*dd+2];
    float d = sqrtf(dx*dx + dy*dy + dz*dz);
    Cb[j] = 0.5f * (cosf(d * 0.31415926535897931f) + 1.0f);
    const float delta = 10.0f / 49.0f;
    const float coeff = -0.5f / (delta * delta);
    #pragma unroll
    for (int gq = 0; gq < 8; ++gq) {
        h8_t hv;
        #pragma unroll
        for (int r = 0; r < 8; ++r) {
            int g = gq * 8 + r;
            float v = 0.0f;
            if (g < NG) { float u = d - (float)g * delta; v = __expf(coeff * u * u); }
            hv[r] = (_Float16)v;
        }
        *(h8_t*)&ea[(size_t)j * 64 + gq * 8] = hv;
    }
}

// ---------------- weight prep: all fp16 single-plane ----------------
__global__ void wprep(const float* __restrict__ Wf1, const float* __restrict__ Wf2,
                      const float* __restrict__ Wl1, const float* __restrict__ Wl2,
                      const float* __restrict__ Wl,
                      _Float16* __restrict__ w1, _Float16* __restrict__ w2,
                      _Float16* __restrict__ wn) {
    int idx = blockIdx.x * 256 + threadIdx.x;
    const int S1 = NI * 128 * 64, S2 = NI * 128 * 128;
    if (idx < S1) {
        int i = idx >> 13, r = idx & 8191, fo = r >> 6, k = r & 63;
        float v = (k < NG) ? Wf1[(size_t)i * NG * 128 + k * 128 + fo] : 0.0f;
        w1[idx] = (_Float16)v;
        return;
    }
    idx -= S1;
    if (idx < S2) {
        int i = idx >> 14, r = idx & 16383, fo = r >> 7, k = r & 127;
        w2[idx] = (_Float16)Wf2[(size_t)i * 128 * 128 + k * 128 + fo];
        return;
    }
    idx -= S2;
    if (idx < 3 * S2) {
        int mi = idx >> 14;
        int r = idx & 16383, fo = r >> 7, k = r & 127;
        int m = mi / NI, i = mi % NI;
        const float* W = (m == 0) ? Wl1 : (m == 1) ? Wl2 : Wl;
        wn[idx] = (_Float16)W[(size_t)i * 128 * 128 + k * 128 + fo];
    }
}

// ---------------- embedding gather ----------------
__global__ void embed_k(const int* __restrict__ z, const float* __restrict__ emb,
                        float* __restrict__ h) {
    int tid = blockIdx.x * 256 + threadIdx.x;
    int n = tid >> 7, f = tid & 127;
    h[tid] = emb[z[n] * HID + f];
}

// ---------------- node GEMM (initial lin1): h(fp32) @ W -> x(fp16) ----------------
__launch_bounds__(256)
__global__ void gemm_node_mfma(const float* __restrict__ A,
                               const _Float16* __restrict__ wt,
                               _Float16* __restrict__ xh) {
    __shared__ _Float16 aS[64 * 136];
    int t = threadIdx.x;
    int mb = blockIdx.x * 64;
    #pragma unroll
    for (int j = 0; j < 8; ++j) {
        int idx = t + j * 256;
        int row = idx >> 5, c4 = idx & 31;
        f4_t v = *(const f4_t*)&A[(size_t)(mb + row) * HID + c4 * 4];
        h4_t hh;
        #pragma unroll
        for (int r = 0; r < 4; ++r) hh[r] = (_Float16)v[r];
        *(h4_t*)&aS[row * 136 + c4 * 4] = hh;
    }
    __syncthreads();

    int wv = t >> 6, lane = t & 63, l15 = lane & 15, quad = lane >> 4;
    f4_t acc[2][4];
    #pragma unroll
    for (int m = 0; m < 2; ++m)
        #pragma unroll
        for (int n = 0; n < 4; ++n) acc[m][n] = (f4_t)0.0f;

    for (int kc = 0; kc < 4; ++kc) {
        int k0 = kc * 32 + quad * 8;
        h8_t a[2];
        #pragma unroll
        for (int m = 0; m < 2; ++m)
            a[m] = *(const h8_t*)&wt[(wv * 32 + m * 16 + l15) * 128 + k0];
        #pragma unroll
        for (int n = 0; n < 4; ++n) {
            h8_t b = *(const h8_t*)&aS[(n * 16 + l15) * 136 + k0];
            #pragma unroll
            for (int m = 0; m < 2; ++m)
                acc[m][n] = __builtin_amdgcn_mfma_f32_16x16x32_f16(a[m], b, acc[m][n], 0, 0, 0);
        }
    }

    #pragma unroll
    for (int n = 0; n < 4; ++n) {
        int el = n * 16 + l15;
        size_t row = (size_t)(mb + el);
        #pragma unroll
        for (int m = 0; m < 2; ++m) {
            int fb = wv * 32 + m * 16 + quad * 4;
            h4_t o;
            #pragma unroll
            for (int r = 0; r < 4; ++r) o[r] = (_Float16)acc[m][n][r];
            *(h4_t*)&xh[row * 128 + fb] = o;
        }
    }
}

// ---------------- fused node: 64-atom tiles; h += ssp(agg@Wl2+bl2)@Wl + bl ; x = h@Wl1next ----------------
__launch_bounds__(256)
__global__ void gemm_node3(const float* __restrict__ agg,
                           const _Float16* __restrict__ w2t, const _Float16* __restrict__ wlt,
                           const _Float16* __restrict__ w1n,
                           const float* __restrict__ bl2, const float* __restrict__ bl,
                           float* __restrict__ h, _Float16* __restrict__ xh) {
    __shared__ _Float16 aS[64 * 136];
    int t = threadIdx.x;
    int mb = blockIdx.x * 64;
    #pragma unroll
    for (int j = 0; j < 8; ++j) {
        int idx = t + j * 256;
        int row = idx >> 5, c4 = idx & 31;
        f4_t v = *(const f4_t*)&agg[(size_t)(mb + row) * HID + c4 * 4];
        h4_t hh;
        #pragma unroll
        for (int r = 0; r < 4; ++r) hh[r] = (_Float16)v[r];
        *(h4_t*)&aS[row * 136 + c4 * 4] = hh;
    }
    __syncthreads();

    int wv = t >> 6, lane = t & 63, l15 = lane & 15, quad = lane >> 4;
    int fq = wv * 32 + quad * 4;
    f4_t acc[2][4];

    // GEMM A: Wl2T @ aggT
    #pragma unroll
    for (int m = 0; m < 2; ++m)
        #pragma unroll
        for (int n = 0; n < 4; ++n) acc[m][n] = (f4_t)0.0f;
    for (int kc = 0; kc < 4; ++kc) {
        int k0 = kc * 32 + quad * 8;
        h8_t a[2];
        #pragma unroll
        for (int m = 0; m < 2; ++m)
            a[m] = *(const h8_t*)&w2t[(wv * 32 + m * 16 + l15) * 128 + k0];
        #pragma unroll
        for (int n = 0; n < 4; ++n) {
            h8_t b = *(const h8_t*)&aS[(n * 16 + l15) * 136 + k0];
            #pragma unroll
            for (int m = 0; m < 2; ++m)
                acc[m][n] = __builtin_amdgcn_mfma_f32_16x16x32_f16(a[m], b, acc[m][n], 0, 0, 0);
        }
    }
    f4_t b2v[2];
    b2v[0] = *(const f4_t*)&bl2[fq]; b2v[1] = *(const f4_t*)&bl2[fq + 16];
    __syncthreads();

    // epilogue A: ssp -> aS
    #pragma unroll
    for (int m = 0; m < 2; ++m)
        #pragma unroll
        for (int n = 0; n < 4; ++n) {
            int el = n * 16 + l15;
            int fb = wv * 32 + m * 16 + quad * 4;
            h4_t hh;
            #pragma unroll
            for (int r = 0; r < 4; ++r)
                hh[r] = (_Float16)ssp_f(acc[m][n][r] + b2v[m][r]);
            *(h4_t*)&aS[el * 136 + fb] = hh;
        }
    __syncthreads();

    // GEMM B: WlT @ t1T
    #pragma unroll
    for (int m = 0; m < 2; ++m)
        #pragma unroll
        for (int n = 0; n < 4; ++n) acc[m][n] = (f4_t)0.0f;
    for (int kc = 0; kc < 4; ++kc) {
        int k0 = kc * 32 + quad * 8;
        h8_t a[2];
        #pragma unroll
        for (int m = 0; m < 2; ++m)
            a[m] = *(const h8_t*)&wlt[(wv * 32 + m * 16 + l15) * 128 + k0];
        #pragma unroll
        for (int n = 0; n < 4; ++n) {
            h8_t b = *(const h8_t*)&aS[(n * 16 + l15) * 136 + k0];
            #pragma unroll
            for (int m = 0; m < 2; ++m)
                acc[m][n] = __builtin_amdgcn_mfma_f32_16x16x32_f16(a[m], b, acc[m][n], 0, 0, 0);
        }
    }
    f4_t blv[2];
    blv[0] = *(const f4_t*)&bl[fq]; blv[1] = *(const f4_t*)&bl[fq + 16];
    __syncthreads();

    // epilogue B: hnew = h + acc + bl; store h; fp16 into aS for GEMM C
    #pragma unroll
    for (int n = 0; n < 4; ++n) {
        int el = n * 16 + l15;
        size_t row = (size_t)(mb + el);
        #pragma unroll
        for (int m = 0; m < 2; ++m) {
            int fb = wv * 32 + m * 16 + quad * 4;
            f4_t hv = *(const f4_t*)&h[row * 128 + fb];
            f4_t o;
            h4_t hh;
            #pragma unroll
            for (int r = 0; r < 4; ++r) {
                o[r] = hv[r] + acc[m][n][r] + blv[m][r];
                hh[r] = (_Float16)o[r];
            }
            *(f4_t*)&h[row * 128 + fb] = o;
            *(h4_t*)&aS[el * 136 + fb] = hh;
        }
    }
    if (!w1n) return;
    __syncthreads();

    // GEMM C: Wl1nextT @ hnewT -> xh
    #pragma unroll
    for (int m = 0; m < 2; ++m)
        #pragma unroll
        for (int n = 0; n < 4; ++n) acc[m][n] = (f4_t)0.0f;
    for (int kc = 0; kc < 4; ++kc) {
        int k0 = kc * 32 + quad * 8;
        h8_t a[2];
        #pragma unroll
        for (int m = 0; m < 2; ++m)
            a[m] = *(const h8_t*)&w1n[(wv * 32 + m * 16 + l15) * 128 + k0];
        #pragma unroll
        for (int n = 0; n < 4; ++n) {
            h8_t b = *(const h8_t*)&aS[(n * 16 + l15) * 136 + k0];
            #pragma unroll
            for (int m = 0; m < 2; ++m)
                acc[m][n] = __builtin_amdgcn_mfma_f32_16x16x32_f16(a[m], b, acc[m][n], 0, 0, 0);
        }
    }
    #pragma unroll
    for (int n = 0; n < 4; ++n) {
        int el = n * 16 + l15;
        size_t row = (size_t)(mb + el);
        #pragma unroll
        for (int m = 0; m < 2; ++m) {
            int fb = wv * 32 + m * 16 + quad * 4;
            h4_t o;
            #pragma unroll
            for (int r = 0; r < 4; ++r) o[r] = (_Float16)acc[m][n][r];
            *(h4_t*)&xh[row * 128 + fb] = o;
        }
    }
}

// ---------------- edge filter: R18 structure + b128-vectorized segmented reduction ----------------
#define T1_LDW 136
#define EA_LDW 72
#define NDST 16

__launch_bounds__(256, 4)
__global__ void edge_filter(const _Float16* __restrict__ xh, float* __restrict__ agg,
                            const int* __restrict__ sSrc, const int* __restrict__ sDst,
                            const int* __restrict__ offs, const float* __restrict__ Cb,
                            const _Float16* __restrict__ ea,
                            const _Float16* __restrict__ w1, const _Float16* __restrict__ w2,
                            const float* __restrict__ bf1, const float* __restrict__ bf2) {
    __shared__ __align__(16) _Float16 eaS[64 * EA_LDW];   // 9.2 KB
    __shared__ __align__(16) _Float16 t1S[64 * T1_LDW];   // 17.4 KB; msg overlays
    __shared__ float accS[NDST * 128];                    // 8 KB
    __shared__ int dstl[2][64];

    _Float16* msg = t1S;

    int t = threadIdx.x;
    int wv = t >> 6, lane = t & 63;
    int l15 = lane & 15, quad = lane >> 4;
    int d0 = blockIdx.x * NDST;
    int estart = offs[d0];
    int ecnt = offs[d0 + NDST] - estart;
    int tmax = (ecnt + 63) >> 6;

    // zero the accumulator
    #pragma unroll
    for (int c = 0; c < 2; ++c)
        *(f4_t*)&accS[(t + c * 256) * 4] = (f4_t)0.0f;

    // persistent fp16 weight fragments
    h8_t w1f[2][2], w2f[4][2];
    #pragma unroll
    for (int kc = 0; kc < 2; ++kc) {
        int k0 = kc * 32 + quad * 8;
        #pragma unroll
        for (int m = 0; m < 2; ++m)
            w1f[kc][m] = *(const h8_t*)&w1[(wv * 32 + m * 16 + l15) * 64 + k0];
    }
    #pragma unroll
    for (int kc = 0; kc < 4; ++kc) {
        int k0 = kc * 32 + quad * 8;
        #pragma unroll
        for (int m = 0; m < 2; ++m)
            w2f[kc][m] = *(const h8_t*)&w2[(wv * 32 + m * 16 + l15) * 128 + k0];
    }
    int fq = wv * 32 + quad * 4;
    f4_t b1v[2], b2v[2];
    b1v[0] = *(const f4_t*)&bf1[fq];  b1v[1] = *(const f4_t*)&bf1[fq + 16];
    b2v[0] = *(const f4_t*)&bf2[fq];  b2v[1] = *(const f4_t*)&bf2[fq + 16];

    for (int tt = 0; tt < tmax; ++tt) {
        int cur = tt & 1;
        int base = estart + tt * 64;
        int lim = ecnt - tt * 64;          // >=1; may exceed 64 for non-last tiles

        // stage eaS (zero-padded), dstl[cur], per-lane meta
        #pragma unroll
        for (int c = 0; c < 2; ++c) {
            int ch = t + c * 256;
            int e = ch >> 3, ks = ch & 7;
            h8_t v = (h8_t)(_Float16)0.0f;
            if (e < lim) v = *(const h8_t*)&ea[(size_t)(base + e) * 64 + ks * 8];
            *(h8_t*)&eaS[e * EA_LDW + ks * 8] = v;
        }
        if (t < 64) {
            int dl = 0;
            if (t < lim) dl = sDst[base + t] - d0;
            dstl[cur][t] = dl;
        }
        int srcn[4];
        float cn[4];
        #pragma unroll
        for (int n = 0; n < 4; ++n) {
            int rel = n * 16 + l15;
            bool ok = rel < lim;
            srcn[n] = ok ? sSrc[base + rel] : 0;
            cn[n]   = ok ? Cb[base + rel] : 0.0f;
        }
        // x[src] gather (overlaps GEMM1)
        h4_t xr[4][2];
        #pragma unroll
        for (int n = 0; n < 4; ++n)
            #pragma unroll
            for (int m = 0; m < 2; ++m)
                xr[n][m] = *(const h4_t*)&xh[(size_t)srcn[n] * HID + wv * 32 + m * 16 + quad * 4];
        __syncthreads();           // barS: eaS/dstl[cur] ready; prev-tile msg+dstl reads done

        // ---- GEMM1: W1(reg) x ea(LDS), 16 MFMA ----
        f4_t acc1[2][4];
        #pragma unroll
        for (int m = 0; m < 2; ++m)
            #pragma unroll
            for (int n = 0; n < 4; ++n) acc1[m][n] = (f4_t)0.0f;
        #pragma unroll
        for (int kc = 0; kc < 2; ++kc) {
            int k0 = kc * 32 + quad * 8;
            h8_t b[4];
            #pragma unroll
            for (int n = 0; n < 4; ++n)
                b[n] = *(const h8_t*)&eaS[(n * 16 + l15) * EA_LDW + k0];
            #pragma unroll
            for (int m = 0; m < 2; ++m)
                #pragma unroll
                for (int n = 0; n < 4; ++n)
                    acc1[m][n] = __builtin_amdgcn_mfma_f32_16x16x32_f16(w1f[kc][m], b[n], acc1[m][n], 0, 0, 0);
        }

        // epilogue1: ssp -> fp16 t1
        #pragma unroll
        for (int m = 0; m < 2; ++m)
            #pragma unroll
            for (int n = 0; n < 4; ++n) {
                int el = n * 16 + l15;
                int fb = wv * 32 + m * 16 + quad * 4;
                h4_t hh;
                #pragma unroll
                for (int r = 0; r < 4; ++r)
                    hh[r] = (_Float16)ssp_f(acc1[m][n][r] + b1v[m][r]);
                *(h4_t*)&t1S[el * T1_LDW + fb] = hh;
            }
        __syncthreads();           // barA: t1 ready

        // ---- GEMM2: W2(reg) x t1(LDS), 32 MFMA ----
        f4_t acc2[2][4];
        #pragma unroll
        for (int m = 0; m < 2; ++m)
            #pragma unroll
            for (int n = 0; n < 4; ++n) acc2[m][n] = (f4_t)0.0f;
        #pragma unroll
        for (int kc = 0; kc < 4; ++kc) {
            int k0 = kc * 32 + quad * 8;
            #pragma unroll
            for (int n = 0; n < 4; ++n) {
                h8_t b = *(const h8_t*)&t1S[(n * 16 + l15) * T1_LDW + k0];
                #pragma unroll
                for (int m = 0; m < 2; ++m)
                    acc2[m][n] = __builtin_amdgcn_mfma_f32_16x16x32_f16(w2f[kc][m], b, acc2[m][n], 0, 0, 0);
            }
        }
        __syncthreads();           // barB: t1 reads done; msg may overlay

        // epilogue2: *C, *x[src] -> msg (fp16); invalid edges have C=0
        #pragma unroll
        for (int n = 0; n < 4; ++n) {
            int el = n * 16 + l15;
            float ce = cn[n];
            #pragma unroll
            for (int m = 0; m < 2; ++m) {
                int fb = wv * 32 + m * 16 + quad * 4;
                h4_t o;
                #pragma unroll
                for (int r = 0; r < 4; ++r)
                    o[r] = (_Float16)((acc2[m][n][r] + b2v[m][r]) * ce * (float)xr[n][m][r]);
                *(h4_t*)&msg[el * T1_LDW + fb] = o;
            }
        }
        __syncthreads();           // barC: msg ready

        // segmented accumulation into accS: thread = (8-feat octet, 4-row segment)
        {
            int fg = t & 15, rs = t >> 4;
            int f0 = fg * 8;
            int i0 = rs * 4;
            int4 dq = *(const int4*)&dstl[cur][i0];
            int dd[4] = {dq.x, dq.y, dq.z, dq.w};
            float run[8];
            #pragma unroll
            for (int k = 0; k < 8; ++k) run[k] = 0.0f;
            int curd = dd[0];
            #pragma unroll
            for (int i = 0; i < 4; ++i) {
                int dnow = dd[i];
                if (dnow != curd) {
                    #pragma unroll
                    for (int k = 0; k < 8; ++k) atomicAdd(&accS[curd * 128 + f0 + k], run[k]);
                    #pragma unroll
                    for (int k = 0; k < 8; ++k) run[k] = 0.0f;
                    curd = dnow;
                }
                h8_t v = *(const h8_t*)&msg[(i0 + i) * T1_LDW + f0];
                #pragma unroll
                for (int k = 0; k < 8; ++k) run[k] += (float)v[k];
            }
            #pragma unroll
            for (int k = 0; k < 8; ++k) atomicAdd(&accS[curd * 128 + f0 + k], run[k]);
        }
        // no barD: next tile's barS fences msg/dstl[cur] reads
    }
    __syncthreads();               // final: all reduction atomics landed

    // write the 16 owned agg rows with plain coalesced stores
    float* dstp = &agg[(size_t)d0 * HID];
    #pragma unroll
    for (int c = 0; c < 2; ++c) {
        int idx = t + c * 256;
        *(f4_t*)&dstp[idx * 4] = *(const f4_t*)&accS[idx * 4];
    }
}

// ---------------- readout ----------------
__launch_bounds__(256)
__global__ void readout1(const float* __restrict__ h, const float* __restrict__ Wo1,
                         const float* __restrict__ bo1, const float* __restrict__ Wo2,
                         const float* __restrict__ bo2, float* __restrict__ accum) {
    __shared__ float w1[128 * 64];
    __shared__ float part[4];
    int t = threadIdx.x;
    for (int i = t; i < 128 * 16; i += 256)
        ((float4*)w1)[i] = ((const float4*)Wo1)[i];
    __syncthreads();
    int f = t & 63, wv = t >> 6;
    float b = bo1[f], w2v = Wo2[f];
    float lsum = 0.0f;
    for (int a = 0; a < 16; ++a) {
        int n = blockIdx.x * 64 + wv * 16 + a;
        const float* hr = &h[(size_t)n * HID];
        float acc = b;
        #pragma unroll 16
        for (int k = 0; k < 128; ++k)
            acc = fmaf(hr[k], w1[k*64 + f], acc);
        lsum += ssp_f(acc) * w2v;
    }
    #pragma unroll
    for (int off = 32; off > 0; off >>= 1)
        lsum += __shfl_down(lsum, off, 64);
    if (f == 0) part[wv] = lsum;
    __syncthreads();
    if (t == 0)
        atomicAdd(accum, part[0] + part[1] + part[2] + part[3] + 64.0f * bo2[0]);
}

__global__ void readout2(const float* __restrict__ accum, float* __restrict__ out) {
    out[0] = fmaxf(accum[0], 0.0f);
}

extern "C" void kernel_launch(void* const* d_in, const int* in_sizes, int n_in,
                              void* d_out, int out_size, void* d_ws, size_t ws_size,
                              hipStream_t stream) {
    const int*   z   = (const int*)d_in[0];
    const float* pos = (const float*)d_in[1];
    const int*   ei  = (const int*)d_in[2];
    const float* emb = (const float*)d_in[3];
    const float* Wf1 = (const float*)d_in[4];
    const float* bf1 = (const float*)d_in[5];
    const float* Wf2 = (const float*)d_in[6];
    const float* bf2 = (const float*)d_in[7];
    const float* Wl1 = (const float*)d_in[8];
    const float* Wl2 = (const float*)d_in[9];
    const float* bl2 = (const float*)d_in[10];
    const float* Wl  = (const float*)d_in[11];
    const float* bl  = (const float*)d_in[12];
    const float* Wo1 = (const float*)d_in[13];
    const float* bo1 = (const float*)d_in[14];
    const float* Wo2 = (const float*)d_in[15];
    const float* bo2 = (const float*)d_in[16];
    float* out = (float*)d_out;

    _Float16* w1 = (_Float16*)d_ws;                        // NI*8192
    _Float16* w2 = w1 + NI * 8192;                         // NI*16384
    _Float16* wn = w2 + NI * 16384;                        // 3*NI*16384
    _Float16* ea = wn + 3 * NI * 16384;                    // E*64
    _Float16* xh = ea + (size_t)NEDGE * 64;                // N*128
    float* Cb  = (float*)(xh + (size_t)NATOM * 128);       // E
    float* h   = Cb + NEDGE;
    float* agg = h + (size_t)NATOM * HID;
    float* accum = agg + (size_t)NATOM * HID;
    int* cnt  = (int*)(accum + 4);
    int* offs = cnt + NATOM;
    int* sSrc = offs + NATOM + 4;
    int* sDst = sSrc + NEDGE;

    fill0<<<NATOM/4/256, 256, 0, stream>>>((float*)cnt, NATOM/4);
    hist_k<<<NEDGE/256, 256, 0, stream>>>(ei, cnt);
    scan_k<<<1, 256, 0, stream>>>(cnt, offs);
    fill0<<<NATOM/4/256, 256, 0, stream>>>((float*)cnt, NATOM/4);
    scatter_k<<<NEDGE/256, 256, 0, stream>>>(ei, offs, cnt, sSrc, sDst);

    edge_pre<<<NEDGE/256, 256, 0, stream>>>(pos, sSrc, sDst, ea, Cb);
    wprep<<<(NI*8192 + NI*16384 + 3*NI*16384)/256, 256, 0, stream>>>(
        Wf1, Wf2, Wl1, Wl2, Wl, w1, w2, wn);
    embed_k<<<(NATOM*HID)/256, 256, 0, stream>>>(z, emb, h);

    gemm_node_mfma<<<NATOM/64, 256, 0, stream>>>(h, wn, xh);
    for (int i = 0; i < NI; ++i) {
        edge_filter<<<NATOM/NDST, 256, 0, stream>>>(xh, agg, sSrc, sDst, offs, Cb, ea,
            w1 + (size_t)i*8192, w2 + (size_t)i*16384,
            bf1 + i*HID, bf2 + i*HID);
        const _Float16* w1n = (i < NI-1) ? wn + (size_t)(i+1)*16384 : nullptr;
        gemm_node3<<<NATOM/64, 256, 0, stream>>>(agg,
            wn + (size_t)(1*NI+i)*16384, wn + (size_t)(2*NI+i)*16384,
            w1n, bl2 + i*HID, bl + i*HID, h, xh);
    }
    fill0<<<1, 256, 0, stream>>>(accum, 1);
    readout1<<<NATOM/64, 256, 0, stream>>>(h, Wo1, bo1, Wo2, bo2, accum);
    readout2<<<1, 1, 0, stream>>>(accum, out);
}

// Round 20
// 776.443 us; speedup vs baseline: 1.1856x; 1.1856x over previous
//
#include <hip/hip_runtime.h>
#include <math.h>

#define NATOM 16384
#define NEDGE 262144
#define HID 128
#define NG 50
#define NI 6

typedef _Float16 h8_t __attribute__((ext_vector_type(8)));
typedef _Float16 h4_t __attribute__((ext_vector_type(4)));
typedef float    f4_t __attribute__((ext_vector_type(4)));

__device__ __forceinline__ float ssp_f(float v) {
    float e = __expf(-fabsf(v));
    return fmaxf(v, 0.0f) + __logf(1.0f + e) - 0.69314718055994531f;
}

// ---------------- counting sort by dst ----------------
__global__ void fill0(float* __restrict__ p, int n4) {
    int i = blockIdx.x * 256 + threadIdx.x;
    if (i < n4) ((float4*)p)[i] = make_float4(0.f, 0.f, 0.f, 0.f);
}

__global__ void hist_k(const int* __restrict__ ei, int* __restrict__ cnt) {
    int e = blockIdx.x * 256 + threadIdx.x;
    if (e < NEDGE) atomicAdd(&cnt[ei[NEDGE + e]], 1);
}

__global__ void scan_k(const int* __restrict__ cnt, int* __restrict__ offs) {
    __shared__ int part[256];
    int t = threadIdx.x;
    int base = t * 64;
    int s = 0;
    for (int i = 0; i < 64; ++i) s += cnt[base + i];
    part[t] = s;
    __syncthreads();
    for (int off = 1; off < 256; off <<= 1) {
        int v = (t >= off) ? part[t - off] : 0;
        __syncthreads();
        part[t] += v;
        __syncthreads();
    }
    int r = part[t] - s;
    for (int i = 0; i < 64; ++i) { offs[base + i] = r; r += cnt[base + i]; }
    if (t == 255) offs[NATOM] = r;
}

__global__ void scatter_k(const int* __restrict__ ei, const int* __restrict__ offs,
                          int* __restrict__ cnt, int* __restrict__ sSrc, int* __restrict__ sDst) {
    int e = blockIdx.x * 256 + threadIdx.x;
    if (e >= NEDGE) return;
    int d = ei[NEDGE + e];
    int r = atomicAdd(&cnt[d], 1);
    int j = offs[d] + r;
    sSrc[j] = ei[e];
    sDst[j] = d;
}

// ---------------- edge precompute: gaussians fp16 edge-major [e][64] ----------------
__global__ void edge_pre(const float* __restrict__ pos,
                         const int* __restrict__ sSrc, const int* __restrict__ sDst,
                         _Float16* __restrict__ ea, float* __restrict__ Cb) {
    int j = blockIdx.x * 256 + threadIdx.x;
    if (j >= NEDGE) return;
    int s = sSrc[j], dd = sDst[j];
    float dx = pos[3*s]   - pos[3*dd];
    float dy = pos[3*s+1] - pos[3*dd+1];
    float dz = pos[3*s+2] - pos[3*dd+2];
    float d = sqrtf(dx*dx + dy*dy + dz*dz);
    Cb[j] = 0.5f * (cosf(d * 0.31415926535897931f) + 1.0f);
    const float delta = 10.0f / 49.0f;
    const float coeff = -0.5f / (delta * delta);
    #pragma unroll
    for (int gq = 0; gq < 8; ++gq) {
        h8_t hv;
        #pragma unroll
        for (int r = 0; r < 8; ++r) {
            int g = gq * 8 + r;
            float v = 0.0f;
            if (g < NG) { float u = d - (float)g * delta; v = __expf(coeff * u * u); }
            hv[r] = (_Float16)v;
        }
        *(h8_t*)&ea[(size_t)j * 64 + gq * 8] = hv;
    }
}

// ---------------- weight prep: all fp16 single-plane ----------------
__global__ void wprep(const float* __restrict__ Wf1, const float* __restrict__ Wf2,
                      const float* __restrict__ Wl1, const float* __restrict__ Wl2,
                      const float* __restrict__ Wl,
                      _Float16* __restrict__ w1, _Float16* __restrict__ w2,
                      _Float16* __restrict__ wn) {
    int idx = blockIdx.x * 256 + threadIdx.x;
    const int S1 = NI * 128 * 64, S2 = NI * 128 * 128;
    if (idx < S1) {
        int i = idx >> 13, r = idx & 8191, fo = r >> 6, k = r & 63;
        float v = (k < NG) ? Wf1[(size_t)i * NG * 128 + k * 128 + fo] : 0.0f;
        w1[idx] = (_Float16)v;
        return;
    }
    idx -= S1;
    if (idx < S2) {
        int i = idx >> 14, r = idx & 16383, fo = r >> 7, k = r & 127;
        w2[idx] = (_Float16)Wf2[(size_t)i * 128 * 128 + k * 128 + fo];
        return;
    }
    idx -= S2;
    if (idx < 3 * S2) {
        int mi = idx >> 14;
        int r = idx & 16383, fo = r >> 7, k = r & 127;
        int m = mi / NI, i = mi % NI;
        const float* W = (m == 0) ? Wl1 : (m == 1) ? Wl2 : Wl;
        wn[idx] = (_Float16)W[(size_t)i * 128 * 128 + k * 128 + fo];
    }
}

// ---------------- embedding gather ----------------
__global__ void embed_k(const int* __restrict__ z, const float* __restrict__ emb,
                        float* __restrict__ h) {
    int tid = blockIdx.x * 256 + threadIdx.x;
    int n = tid >> 7, f = tid & 127;
    h[tid] = emb[z[n] * HID + f];
}

// ---------------- node GEMM (initial lin1): h(fp32) @ W -> x(fp16) ----------------
__launch_bounds__(256)
__global__ void gemm_node_mfma(const float* __restrict__ A,
                               const _Float16* __restrict__ wt,
                               _Float16* __restrict__ xh) {
    __shared__ _Float16 aS[64 * 136];
    int t = threadIdx.x;
    int mb = blockIdx.x * 64;
    #pragma unroll
    for (int j = 0; j < 8; ++j) {
        int idx = t + j * 256;
        int row = idx >> 5, c4 = idx & 31;
        f4_t v = *(const f4_t*)&A[(size_t)(mb + row) * HID + c4 * 4];
        h4_t hh;
        #pragma unroll
        for (int r = 0; r < 4; ++r) hh[r] = (_Float16)v[r];
        *(h4_t*)&aS[row * 136 + c4 * 4] = hh;
    }
    __syncthreads();

    int wv = t >> 6, lane = t & 63, l15 = lane & 15, quad = lane >> 4;
    f4_t acc[2][4];
    #pragma unroll
    for (int m = 0; m < 2; ++m)
        #pragma unroll
        for (int n = 0; n < 4; ++n) acc[m][n] = (f4_t)0.0f;

    for (int kc = 0; kc < 4; ++kc) {
        int k0 = kc * 32 + quad * 8;
        h8_t a[2];
        #pragma unroll
        for (int m = 0; m < 2; ++m)
            a[m] = *(const h8_t*)&wt[(wv * 32 + m * 16 + l15) * 128 + k0];
        #pragma unroll
        for (int n = 0; n < 4; ++n) {
            h8_t b = *(const h8_t*)&aS[(n * 16 + l15) * 136 + k0];
            #pragma unroll
            for (int m = 0; m < 2; ++m)
                acc[m][n] = __builtin_amdgcn_mfma_f32_16x16x32_f16(a[m], b, acc[m][n], 0, 0, 0);
        }
    }

    #pragma unroll
    for (int n = 0; n < 4; ++n) {
        int el = n * 16 + l15;
        size_t row = (size_t)(mb + el);
        #pragma unroll
        for (int m = 0; m < 2; ++m) {
            int fb = wv * 32 + m * 16 + quad * 4;
            h4_t o;
            #pragma unroll
            for (int r = 0; r < 4; ++r) o[r] = (_Float16)acc[m][n][r];
            *(h4_t*)&xh[row * 128 + fb] = o;
        }
    }
}

// ---------------- fused node: 64-atom tiles; h += ssp(agg@Wl2+bl2)@Wl + bl ; x = h@Wl1next ----------------
__launch_bounds__(256)
__global__ void gemm_node3(const float* __restrict__ agg,
                           const _Float16* __restrict__ w2t, const _Float16* __restrict__ wlt,
                           const _Float16* __restrict__ w1n,
                           const float* __restrict__ bl2, const float* __restrict__ bl,
                           float* __restrict__ h, _Float16* __restrict__ xh) {
    __shared__ _Float16 aS[64 * 136];
    int t = threadIdx.x;
    int mb = blockIdx.x * 64;
    #pragma unroll
    for (int j = 0; j < 8; ++j) {
        int idx = t + j * 256;
        int row = idx >> 5, c4 = idx & 31;
        f4_t v = *(const f4_t*)&agg[(size_t)(mb + row) * HID + c4 * 4];
        h4_t hh;
        #pragma unroll
        for (int r = 0; r < 4; ++r) hh[r] = (_Float16)v[r];
        *(h4_t*)&aS[row * 136 + c4 * 4] = hh;
    }
    __syncthreads();

    int wv = t >> 6, lane = t & 63, l15 = lane & 15, quad = lane >> 4;
    int fq = wv * 32 + quad * 4;
    f4_t acc[2][4];

    // GEMM A: Wl2T @ aggT
    #pragma unroll
    for (int m = 0; m < 2; ++m)
        #pragma unroll
        for (int n = 0; n < 4; ++n) acc[m][n] = (f4_t)0.0f;
    for (int kc = 0; kc < 4; ++kc) {
        int k0 = kc * 32 + quad * 8;
        h8_t a[2];
        #pragma unroll
        for (int m = 0; m < 2; ++m)
            a[m] = *(const h8_t*)&w2t[(wv * 32 + m * 16 + l15) * 128 + k0];
        #pragma unroll
        for (int n = 0; n < 4; ++n) {
            h8_t b = *(const h8_t*)&aS[(n * 16 + l15) * 136 + k0];
            #pragma unroll
            for (int m = 0; m < 2; ++m)
                acc[m][n] = __builtin_amdgcn_mfma_f32_16x16x32_f16(a[m], b, acc[m][n], 0, 0, 0);
        }
    }
    f4_t b2v[2];
    b2v[0] = *(const f4_t*)&bl2[fq]; b2v[1] = *(const f4_t*)&bl2[fq + 16];
    __syncthreads();

    // epilogue A: ssp -> aS
    #pragma unroll
    for (int m = 0; m < 2; ++m)
        #pragma unroll
        for (int n = 0; n < 4; ++n) {
            int el = n * 16 + l15;
            int fb = wv * 32 + m * 16 + quad * 4;
            h4_t hh;
            #pragma unroll
            for (int r = 0; r < 4; ++r)
                hh[r] = (_Float16)ssp_f(acc[m][n][r] + b2v[m][r]);
            *(h4_t*)&aS[el * 136 + fb] = hh;
        }
    __syncthreads();

    // GEMM B: WlT @ t1T
    #pragma unroll
    for (int m = 0; m < 2; ++m)
        #pragma unroll
        for (int n = 0; n < 4; ++n) acc[m][n] = (f4_t)0.0f;
    for (int kc = 0; kc < 4; ++kc) {
        int k0 = kc * 32 + quad * 8;
        h8_t a[2];
        #pragma unroll
        for (int m = 0; m < 2; ++m)
            a[m] = *(const h8_t*)&wlt[(wv * 32 + m * 16 + l15) * 128 + k0];
        #pragma unroll
        for (int n = 0; n < 4; ++n) {
            h8_t b = *(const h8_t*)&aS[(n * 16 + l15) * 136 + k0];
            #pragma unroll
            for (int m = 0; m < 2; ++m)
                acc[m][n] = __builtin_amdgcn_mfma_f32_16x16x32_f16(a[m], b, acc[m][n], 0, 0, 0);
        }
    }
    f4_t blv[2];
    blv[0] = *(const f4_t*)&bl[fq]; blv[1] = *(const f4_t*)&bl[fq + 16];
    __syncthreads();

    // epilogue B: hnew = h + acc + bl; store h; fp16 into aS for GEMM C
    #pragma unroll
    for (int n = 0; n < 4; ++n) {
        int el = n * 16 + l15;
        size_t row = (size_t)(mb + el);
        #pragma unroll
        for (int m = 0; m < 2; ++m) {
            int fb = wv * 32 + m * 16 + quad * 4;
            f4_t hv = *(const f4_t*)&h[row * 128 + fb];
            f4_t o;
            h4_t hh;
            #pragma unroll
            for (int r = 0; r < 4; ++r) {
                o[r] = hv[r] + acc[m][n][r] + blv[m][r];
                hh[r] = (_Float16)o[r];
            }
            *(f4_t*)&h[row * 128 + fb] = o;
            *(h4_t*)&aS[el * 136 + fb] = hh;
        }
    }
    if (!w1n) return;
    __syncthreads();

    // GEMM C: Wl1nextT @ hnewT -> xh
    #pragma unroll
    for (int m = 0; m < 2; ++m)
        #pragma unroll
        for (int n = 0; n < 4; ++n) acc[m][n] = (f4_t)0.0f;
    for (int kc = 0; kc < 4; ++kc) {
        int k0 = kc * 32 + quad * 8;
        h8_t a[2];
        #pragma unroll
        for (int m = 0; m < 2; ++m)
            a[m] = *(const h8_t*)&w1n[(wv * 32 + m * 16 + l15) * 128 + k0];
        #pragma unroll
        for (int n = 0; n < 4; ++n) {
            h8_t b = *(const h8_t*)&aS[(n * 16 + l15) * 136 + k0];
            #pragma unroll
            for (int m = 0; m < 2; ++m)
                acc[m][n] = __builtin_amdgcn_mfma_f32_16x16x32_f16(a[m], b, acc[m][n], 0, 0, 0);
        }
    }
    #pragma unroll
    for (int n = 0; n < 4; ++n) {
        int el = n * 16 + l15;
        size_t row = (size_t)(mb + el);
        #pragma unroll
        for (int m = 0; m < 2; ++m) {
            int fb = wv * 32 + m * 16 + quad * 4;
            h4_t o;
            #pragma unroll
            for (int r = 0; r < 4; ++r) o[r] = (_Float16)acc[m][n][r];
            *(h4_t*)&xh[row * 128 + fb] = o;
        }
    }
}

// ---------------- edge filter: R18 measured-best config (4 barriers/tile) ----------------
#define T1_LDW 136
#define EA_LDW 72
#define NDST 16

__launch_bounds__(256, 4)
__global__ void edge_filter(const _Float16* __restrict__ xh, float* __restrict__ agg,
                            const int* __restrict__ sSrc, const int* __restrict__ sDst,
                            const int* __restrict__ offs, const float* __restrict__ Cb,
                            const _Float16* __restrict__ ea,
                            const _Float16* __restrict__ w1, const _Float16* __restrict__ w2,
                            const float* __restrict__ bf1, const float* __restrict__ bf2) {
    __shared__ __align__(16) _Float16 eaS[64 * EA_LDW];   // 9.2 KB
    __shared__ __align__(16) _Float16 t1S[64 * T1_LDW];   // 17.4 KB; msg overlays
    __shared__ float accS[NDST * 128];                    // 8 KB
    __shared__ int dstl[2][64];

    _Float16* msg = t1S;

    int t = threadIdx.x;
    int wv = t >> 6, lane = t & 63;
    int l15 = lane & 15, quad = lane >> 4;
    int d0 = blockIdx.x * NDST;
    int estart = offs[d0];
    int ecnt = offs[d0 + NDST] - estart;
    int tmax = (ecnt + 63) >> 6;

    // zero the accumulator
    #pragma unroll
    for (int c = 0; c < 2; ++c)
        *(f4_t*)&accS[(t + c * 256) * 4] = (f4_t)0.0f;

    // persistent fp16 weight fragments
    h8_t w1f[2][2], w2f[4][2];
    #pragma unroll
    for (int kc = 0; kc < 2; ++kc) {
        int k0 = kc * 32 + quad * 8;
        #pragma unroll
        for (int m = 0; m < 2; ++m)
            w1f[kc][m] = *(const h8_t*)&w1[(wv * 32 + m * 16 + l15) * 64 + k0];
    }
    #pragma unroll
    for (int kc = 0; kc < 4; ++kc) {
        int k0 = kc * 32 + quad * 8;
        #pragma unroll
        for (int m = 0; m < 2; ++m)
            w2f[kc][m] = *(const h8_t*)&w2[(wv * 32 + m * 16 + l15) * 128 + k0];
    }
    int fq = wv * 32 + quad * 4;
    f4_t b1v[2], b2v[2];
    b1v[0] = *(const f4_t*)&bf1[fq];  b1v[1] = *(const f4_t*)&bf1[fq + 16];
    b2v[0] = *(const f4_t*)&bf2[fq];  b2v[1] = *(const f4_t*)&bf2[fq + 16];

    for (int tt = 0; tt < tmax; ++tt) {
        int cur = tt & 1;
        int base = estart + tt * 64;
        int lim = ecnt - tt * 64;          // >=1; may exceed 64 for non-last tiles

        // stage eaS (zero-padded), dstl[cur], per-lane meta
        #pragma unroll
        for (int c = 0; c < 2; ++c) {
            int ch = t + c * 256;
            int e = ch >> 3, ks = ch & 7;
            h8_t v = (h8_t)(_Float16)0.0f;
            if (e < lim) v = *(const h8_t*)&ea[(size_t)(base + e) * 64 + ks * 8];
            *(h8_t*)&eaS[e * EA_LDW + ks * 8] = v;
        }
        if (t < 64) {
            int dl = 0;
            if (t < lim) dl = sDst[base + t] - d0;
            dstl[cur][t] = dl;
        }
        int srcn[4];
        float cn[4];
        #pragma unroll
        for (int n = 0; n < 4; ++n) {
            int rel = n * 16 + l15;
            bool ok = rel < lim;
            srcn[n] = ok ? sSrc[base + rel] : 0;
            cn[n]   = ok ? Cb[base + rel] : 0.0f;
        }
        // x[src] gather (overlaps GEMM1)
        h4_t xr[4][2];
        #pragma unroll
        for (int n = 0; n < 4; ++n)
            #pragma unroll
            for (int m = 0; m < 2; ++m)
                xr[n][m] = *(const h4_t*)&xh[(size_t)srcn[n] * HID + wv * 32 + m * 16 + quad * 4];
        __syncthreads();           // barS: eaS/dstl[cur] ready; prev-tile msg+dstl reads done

        // ---- GEMM1: W1(reg) x ea(LDS), 16 MFMA ----
        f4_t acc1[2][4];
        #pragma unroll
        for (int m = 0; m < 2; ++m)
            #pragma unroll
            for (int n = 0; n < 4; ++n) acc1[m][n] = (f4_t)0.0f;
        #pragma unroll
        for (int kc = 0; kc < 2; ++kc) {
            int k0 = kc * 32 + quad * 8;
            h8_t b[4];
            #pragma unroll
            for (int n = 0; n < 4; ++n)
                b[n] = *(const h8_t*)&eaS[(n * 16 + l15) * EA_LDW + k0];
            #pragma unroll
            for (int m = 0; m < 2; ++m)
                #pragma unroll
                for (int n = 0; n < 4; ++n)
                    acc1[m][n] = __builtin_amdgcn_mfma_f32_16x16x32_f16(w1f[kc][m], b[n], acc1[m][n], 0, 0, 0);
        }

        // epilogue1: ssp -> fp16 t1
        #pragma unroll
        for (int m = 0; m < 2; ++m)
            #pragma unroll
            for (int n = 0; n < 4; ++n) {
                int el = n * 16 + l15;
                int fb = wv * 32 + m * 16 + quad * 4;
                h4_t hh;
                #pragma unroll
                for (int r = 0; r < 4; ++r)
                    hh[r] = (_Float16)ssp_f(acc1[m][n][r] + b1v[m][r]);
                *(h4_t*)&t1S[el * T1_LDW + fb] = hh;
            }
        __syncthreads();           // barA: t1 ready

        // ---- GEMM2: W2(reg) x t1(LDS), 32 MFMA ----
        f4_t acc2[2][4];
        #pragma unroll
        for (int m = 0; m < 2; ++m)
            #pragma unroll
            for (int n = 0; n < 4; ++n) acc2[m][n] = (f4_t)0.0f;
        #pragma unroll
        for (int kc = 0; kc < 4; ++kc) {
            int k0 = kc * 32 + quad * 8;
            #pragma unroll
            for (int n = 0; n < 4; ++n) {
                h8_t b = *(const h8_t*)&t1S[(n * 16 + l15) * T1_LDW + k0];
                #pragma unroll
                for (int m = 0; m < 2; ++m)
                    acc2[m][n] = __builtin_amdgcn_mfma_f32_16x16x32_f16(w2f[kc][m], b, acc2[m][n], 0, 0, 0);
            }
        }
        __syncthreads();           // barB: t1 reads done; msg may overlay

        // epilogue2: *C, *x[src] -> msg (fp16); invalid edges have C=0
        #pragma unroll
        for (int n = 0; n < 4; ++n) {
            int el = n * 16 + l15;
            float ce = cn[n];
            #pragma unroll
            for (int m = 0; m < 2; ++m) {
                int fb = wv * 32 + m * 16 + quad * 4;
                h4_t o;
                #pragma unroll
                for (int r = 0; r < 4; ++r)
                    o[r] = (_Float16)((acc2[m][n][r] + b2v[m][r]) * ce * (float)xr[n][m][r]);
                *(h4_t*)&msg[el * T1_LDW + fb] = o;
            }
        }
        __syncthreads();           // barC: msg ready

        // segmented accumulation into LDS accS (column-serial, measured best)
        {
            int f = t & 127, hf = t >> 7;
            int ib = hf * 32;
            float run = 0.0f;
            int cur2 = dstl[cur][ib];
            for (int i = ib; i < ib + 32; ++i) {
                int dnow = dstl[cur][i];
                if (dnow != cur2) {
                    atomicAdd(&accS[cur2 * 128 + f], run);
                    run = 0.0f;
                    cur2 = dnow;
                }
                run += (float)msg[i * T1_LDW + f];
            }
            atomicAdd(&accS[cur2 * 128 + f], run);
        }
        // no barD: next tile's barS fences msg/dstl[cur] reads
    }
    __syncthreads();               // final: all reduction atomics landed

    // write the 16 owned agg rows with plain coalesced stores
    float* dstp = &agg[(size_t)d0 * HID];
    #pragma unroll
    for (int c = 0; c < 2; ++c) {
        int idx = t + c * 256;
        *(f4_t*)&dstp[idx * 4] = *(const f4_t*)&accS[idx * 4];
    }
}

// ---------------- readout ----------------
__launch_bounds__(256)
__global__ void readout1(const float* __restrict__ h, const float* __restrict__ Wo1,
                         const float* __restrict__ bo1, const float* __restrict__ Wo2,
                         const float* __restrict__ bo2, float* __restrict__ accum) {
    __shared__ float w1[128 * 64];
    __shared__ float part[4];
    int t = threadIdx.x;
    for (int i = t; i < 128 * 16; i += 256)
        ((float4*)w1)[i] = ((const float4*)Wo1)[i];
    __syncthreads();
    int f = t & 63, wv = t >> 6;
    float b = bo1[f], w2v = Wo2[f];
    float lsum = 0.0f;
    for (int a = 0; a < 16; ++a) {
        int n = blockIdx.x * 64 + wv * 16 + a;
        const float* hr = &h[(size_t)n * HID];
        float acc = b;
        #pragma unroll 16
        for (int k = 0; k < 128; ++k)
            acc = fmaf(hr[k], w1[k*64 + f], acc);
        lsum += ssp_f(acc) * w2v;
    }
    #pragma unroll
    for (int off = 32; off > 0; off >>= 1)
        lsum += __shfl_down(lsum, off, 64);
    if (f == 0) part[wv] = lsum;
    __syncthreads();
    if (t == 0)
        atomicAdd(accum, part[0] + part[1] + part[2] + part[3] + 64.0f * bo2[0]);
}

__global__ void readout2(const float* __restrict__ accum, float* __restrict__ out) {
    out[0] = fmaxf(accum[0], 0.0f);
}

extern "C" void kernel_launch(void* const* d_in, const int* in_sizes, int n_in,
                              void* d_out, int out_size, void* d_ws, size_t ws_size,
                              hipStream_t stream) {
    const int*   z   = (const int*)d_in[0];
    const float* pos = (const float*)d_in[1];
    const int*   ei  = (const int*)d_in[2];
    const float* emb = (const float*)d_in[3];
    const float* Wf1 = (const float*)d_in[4];
    const float* bf1 = (const float*)d_in[5];
    const float* Wf2 = (const float*)d_in[6];
    const float* bf2 = (const float*)d_in[7];
    const float* Wl1 = (const float*)d_in[8];
    const float* Wl2 = (const float*)d_in[9];
    const float* bl2 = (const float*)d_in[10];
    const float* Wl  = (const float*)d_in[11];
    const float* bl  = (const float*)d_in[12];
    const float* Wo1 = (const float*)d_in[13];
    const float* bo1 = (const float*)d_in[14];
    const float* Wo2 = (const float*)d_in[15];
    const float* bo2 = (const float*)d_in[16];
    float* out = (float*)d_out;

    _Float16* w1 = (_Float16*)d_ws;                        // NI*8192
    _Float16* w2 = w1 + NI * 8192;                         // NI*16384
    _Float16* wn = w2 + NI * 16384;                        // 3*NI*16384
    _Float16* ea = wn + 3 * NI * 16384;                    // E*64
    _Float16* xh = ea + (size_t)NEDGE * 64;                // N*128
    float* Cb  = (float*)(xh + (size_t)NATOM * 128);       // E
    float* h   = Cb + NEDGE;
    float* agg = h + (size_t)NATOM * HID;
    float* accum = agg + (size_t)NATOM * HID;
    int* cnt  = (int*)(accum + 4);
    int* offs = cnt + NATOM;
    int* sSrc = offs + NATOM + 4;
    int* sDst = sSrc + NEDGE;

    fill0<<<NATOM/4/256, 256, 0, stream>>>((float*)cnt, NATOM/4);
    hist_k<<<NEDGE/256, 256, 0, stream>>>(ei, cnt);
    scan_k<<<1, 256, 0, stream>>>(cnt, offs);
    fill0<<<NATOM/4/256, 256, 0, stream>>>((float*)cnt, NATOM/4);
    scatter_k<<<NEDGE/256, 256, 0, stream>>>(ei, offs, cnt, sSrc, sDst);

    edge_pre<<<NEDGE/256, 256, 0, stream>>>(pos, sSrc, sDst, ea, Cb);
    wprep<<<(NI*8192 + NI*16384 + 3*NI*16384)/256, 256, 0, stream>>>(
        Wf1, Wf2, Wl1, Wl2, Wl, w1, w2, wn);
    embed_k<<<(NATOM*HID)/256, 256, 0, stream>>>(z, emb, h);

    gemm_node_mfma<<<NATOM/64, 256, 0, stream>>>(h, wn, xh);
    for (int i = 0; i < NI; ++i) {
        edge_filter<<<NATOM/NDST, 256, 0, stream>>>(xh, agg, sSrc, sDst, offs, Cb, ea,
            w1 + (size_t)i*8192, w2 + (size_t)i*16384,
            bf1 + i*HID, bf2 + i*HID);
        const _Float16* w1n = (i < NI-1) ? wn + (size_t)(i+1)*16384 : nullptr;
        gemm_node3<<<NATOM/64, 256, 0, stream>>>(agg,
            wn + (size_t)(1*NI+i)*16384, wn + (size_t)(2*NI+i)*16384,
            w1n, bl2 + i*HID, bl + i*HID, h, xh);
    }
    fill0<<<1, 256, 0, stream>>>(accum, 1);
    readout1<<<NATOM/64, 256, 0, stream>>>(h, Wo1, bo1, Wo2, bo2, accum);
    readout2<<<1, 1, 0, stream>>>(accum, out);
}